// Round 4
// baseline (138.562 us; speedup 1.0000x reference)
//
#include <hip/hip_runtime.h>
#include <float.h>
#include <math.h>

#define KP 500000
#define KN 25000
#define KK 30
#define KD 128

typedef float f32x4 __attribute__((ext_vector_type(4)));

__device__ __forceinline__ unsigned short f2bf_rne(float x) {
    // round-to-nearest-even fp32 -> bf16
    unsigned int u = __float_as_uint(x);
    return (unsigned short)((u + 0x7FFFu + ((u >> 16) & 1u)) >> 16);
}

// ---------------------------------------------------------------------------
// Kernel 0: mark referenced pairs (scope is 1-based; 0 = padding).
// ---------------------------------------------------------------------------
__global__ __launch_bounds__(256) void mark_kernel(
    const int* __restrict__ scope, unsigned char* __restrict__ flags, int total)
{
    int i = blockIdx.x * 256 + threadIdx.x;
    const int stride = gridDim.x * 256;
    for (; i < total; i += stride) {
        const int ik = scope[i];
        if (ik > 0) flags[ik - 1] = 1;
    }
}

// ---------------------------------------------------------------------------
// Kernel 1: for each REFERENCED pair p:
//   e[p] = softplus( zf[p]·W[0:128] + zo[p]·W[128:256] )
//   zc[p] = bf16(zo[p])   (compact hot copy for the gather phase)
// 32 lanes per pair, float4 loads; zf non-temporal (single use).
// ---------------------------------------------------------------------------
__global__ __launch_bounds__(256) void edge_score_kernel(
    const float* __restrict__ zf, const float* __restrict__ zo,
    const float* __restrict__ W, const unsigned char* __restrict__ flags,
    float* __restrict__ e, unsigned short* __restrict__ zc, int P)
{
    const int lane = threadIdx.x & 31;
    const float4 w1 = *(const float4*)(W + lane * 4);        // W[0:128]
    const float4 w2 = *(const float4*)(W + 128 + lane * 4);  // W[128:256]

    const long pair = (long)blockIdx.x * 8 + (threadIdx.x >> 5);
    if (pair >= P) return;
    if (flags && !flags[pair]) return;        // unreferenced: never fetched

    const f32x4 a = __builtin_nontemporal_load(
        (const f32x4*)(zf + pair * KD + lane * 4));
    const float4 b = *(const float4*)(zo + pair * KD + lane * 4);

    if (zc) {                                  // bf16 row copy, coalesced 8B/lane
        ushort4 pk;
        pk.x = f2bf_rne(b.x); pk.y = f2bf_rne(b.y);
        pk.z = f2bf_rne(b.z); pk.w = f2bf_rne(b.w);
        *(ushort4*)(zc + (size_t)pair * KD + lane * 4) = pk;
    }

    float s = a.x * w1.x + a.y * w1.y + a.z * w1.z + a.w * w1.w
            + b.x * w2.x + b.y * w2.y + b.z * w2.z + b.w * w2.w;
    #pragma unroll
    for (int off = 16; off; off >>= 1)
        s += __shfl_xor(s, off, 32);
    if (lane == 0) {
        // numerically stable softplus = max(x,0) + log1p(exp(-|x|))
        e[pair] = fmaxf(s, 0.0f) + log1pf(expf(-fabsf(s)));
    }
}

// ---------------------------------------------------------------------------
// Kernel 2: per output row r: r==0 -> zeros; else node n = r-1:
// masked softmax over <=30 gathered scores, then weighted gather of
// bf16 rows from zc (L3-hot) or fp32 zo rows (fallback).
// One 64-lane wave per row; each lane owns 2 columns.
// ---------------------------------------------------------------------------
__global__ __launch_bounds__(256) void node_gather_kernel(
    const float* __restrict__ e, const float* __restrict__ zo,
    const unsigned short* __restrict__ zc,
    const int* __restrict__ scope, float* __restrict__ out, int Nrows)
{
    const int wave = threadIdx.x >> 6;
    const int lane = threadIdx.x & 63;
    const int r = blockIdx.x * 4 + wave;
    if (r >= Nrows) return;

    const int col = lane * 2;
    if (r == 0) {
        *(float2*)(out + col) = make_float2(0.f, 0.f);
        return;
    }
    const long n = r - 1;

    int   idx = 0;
    float ev  = 0.f;
    if (lane < KK) {
        idx = scope[n * KK + lane];
        if (idx > 0) ev = e[idx - 1];
    }

    const bool valid = (ev != 0.f);
    float logit = valid ? ev : -FLT_MAX;
    float m = logit;
    #pragma unroll
    for (int off = 32; off; off >>= 1)
        m = fmaxf(m, __shfl_xor(m, off, 64));

    float ex = valid ? expf(ev - m) : 0.f;
    float denom = ex;
    #pragma unroll
    for (int off = 32; off; off >>= 1)
        denom += __shfl_xor(denom, off, 64);
    denom = (denom > 0.f) ? denom : 1.f;
    const float alpha = ex / denom;

    float2 acc = make_float2(0.f, 0.f);
    if (zc) {
        #pragma unroll
        for (int k = 0; k < KK; ++k) {
            const int ik = __shfl(idx, k, 64);            // wave-uniform
            if (ik > 0) {
                const float ak = __shfl(alpha, k, 64);
                const unsigned int v =
                    *(const unsigned int*)(zc + (size_t)(ik - 1) * KD + col);
                const float z0 = __uint_as_float(v << 16);
                const float z1 = __uint_as_float(v & 0xFFFF0000u);
                acc.x += ak * z0;
                acc.y += ak * z1;
            }
        }
    } else {
        #pragma unroll
        for (int k = 0; k < KK; ++k) {
            const int ik = __shfl(idx, k, 64);
            if (ik > 0) {
                const float ak = __shfl(alpha, k, 64);
                const float2 z = *(const float2*)(zo + (long)(ik - 1) * KD + col);
                acc.x += ak * z.x;
                acc.y += ak * z.y;
            }
        }
    }
    *(float2*)(out + (long)r * KD + col) = acc;
}

extern "C" void kernel_launch(void* const* d_in, const int* in_sizes, int n_in,
                              void* d_out, int out_size, void* d_ws, size_t ws_size,
                              hipStream_t stream) {
    const float* zf    = (const float*)d_in[0];   // [P, D]
    const float* zo    = (const float*)d_in[1];   // [P, D]
    const int*   scope = (const int*)d_in[2];     // [N, K]
    const float* W     = (const float*)d_in[3];   // [2D, 1]
    float* out = (float*)d_out;                   // [(N+1), D]

    const int P = in_sizes[0] / KD;
    const int N = in_sizes[2] / KK;

    char* w = (char*)d_ws;
    const size_t eB  = (size_t)P * sizeof(float);         // e:    P floats
    const size_t fB  = (size_t)P;                         // flags: P bytes
    const size_t zcB = (size_t)P * KD * sizeof(unsigned short);  // bf16 copy

    float* e = (float*)w;
    unsigned char* flags = nullptr;
    unsigned short* zc = nullptr;
    if (ws_size >= eB + fB) {
        flags = (unsigned char*)(w + eB);
        hipMemsetAsync(flags, 0, fB, stream);
        mark_kernel<<<512, 256, 0, stream>>>(scope, flags, N * KK);
        if (ws_size >= eB + fB + zcB) {
            zc = (unsigned short*)(w + eB + fB);
        }
    }

    {
        const int grid = (P + 7) / 8;                     // 8 pairs / block
        edge_score_kernel<<<grid, 256, 0, stream>>>(zf, zo, W, flags, e, zc, P);
    }
    {
        const int nrows = N + 1;
        const int grid = (nrows + 3) / 4;                 // 4 rows / block
        node_gather_kernel<<<grid, 256, 0, stream>>>(e, zo, zc, scope, out, nrows);
    }
}

// Round 5
// 72.229 us; speedup vs baseline: 1.9184x; 1.9184x over previous
//
#include <hip/hip_runtime.h>
#include <float.h>
#include <math.h>

#define KP 500000
#define KN 25000
#define KK 30
#define KD 128

// ---------------------------------------------------------------------------
// Fully fused GAT layer, spill-proof edition. One 64-lane wave per output row.
// Wave = two 32-lane halves; iteration t: half h computes neighbor k = 2t+h.
//   - lane owns 4 columns (c = (lane&31)*4), float4 loads (1 KB / wave / inst)
//   - e_k = softplus(zf[ik]·W1 + zo[ik]·W2): per-half 5-round butterfly
//   - un-normalized softmax (e <= ~8 so exp(e) <= ~3e3, no overflow):
//     denom += exp(e); acc += exp(e) * zo_slice   -- no arrays, ~30 live VGPRs
//   - padding (ik==0): clamp row to 0 (L1-hot), weight forced to 0
//   - final: merge the two halves via 5 cross-half shuffles, normalize, store.
// ---------------------------------------------------------------------------
__global__ __launch_bounds__(256, 4) void fused_gat_kernel(
    const float* __restrict__ zf, const float* __restrict__ zo,
    const int* __restrict__ scope, const float* __restrict__ W,
    float* __restrict__ out, int Nrows)
{
    const int wave = threadIdx.x >> 6;
    const int lane = threadIdx.x & 63;
    const int r = blockIdx.x * 4 + wave;
    if (r >= Nrows) return;

    const int c    = (lane & 31) * 4;   // column base (same in both halves)
    const int half = lane >> 5;         // 0 or 1

    if (r == 0) {
        if (half == 0) *(float4*)(out + c) = make_float4(0.f, 0.f, 0.f, 0.f);
        return;
    }
    const long n = r - 1;

    const float4 w1 = *(const float4*)(W + c);        // W[0:128] slice
    const float4 w2 = *(const float4*)(W + KD + c);   // W[128:256] slice

    // lane k (k<30) holds this node's k-th neighbor pair index (1-based, 0=pad)
    const int idxl = (lane < KK) ? scope[n * KK + lane] : 0;

    float  denom = 0.f;
    float4 acc = make_float4(0.f, 0.f, 0.f, 0.f);

    #pragma unroll
    for (int it = 0; it < KK / 2; ++it) {
        const int k  = 2 * it + half;                 // this half's neighbor
        const int ik = __shfl(idxl, k, 64);
        const bool valid = (ik > 0);
        const long row = valid ? (long)(ik - 1) * KD : 0;  // pad -> row 0 (hot)

        const float4 a = *(const float4*)(zf + row + c);
        const float4 b = *(const float4*)(zo + row + c);

        float s = a.x * w1.x + a.y * w1.y + a.z * w1.z + a.w * w1.w
                + b.x * w2.x + b.y * w2.y + b.z * w2.z + b.w * w2.w;
        #pragma unroll
        for (int off = 16; off; off >>= 1)
            s += __shfl_xor(s, off, 32);              // reduce within half
        // stable softplus via fast intrinsics
        const float t = __expf(-fabsf(s));
        const float e = fmaxf(s, 0.f) + __logf(1.f + t);
        // un-normalized softmax weight (exact same ratio as max-subtracted ref)
        const float p = valid ? __expf(e) : 0.f;
        denom += p;
        acc.x += p * b.x; acc.y += p * b.y;
        acc.z += p * b.z; acc.w += p * b.w;
    }

    // merge the two halves (both end up with the full sum)
    const float od = __shfl_xor(denom, 32, 64);
    float4 oa;
    oa.x = __shfl_xor(acc.x, 32, 64);
    oa.y = __shfl_xor(acc.y, 32, 64);
    oa.z = __shfl_xor(acc.z, 32, 64);
    oa.w = __shfl_xor(acc.w, 32, 64);
    const float total = denom + od;
    const float inv = 1.f / fmaxf(total, 1e-30f);     // total==0 -> acc==0 -> out 0
    float4 o;
    o.x = (acc.x + oa.x) * inv;
    o.y = (acc.y + oa.y) * inv;
    o.z = (acc.z + oa.z) * inv;
    o.w = (acc.w + oa.w) * inv;

    if (half == 0)
        *(float4*)(out + (long)r * KD + c) = o;
}

extern "C" void kernel_launch(void* const* d_in, const int* in_sizes, int n_in,
                              void* d_out, int out_size, void* d_ws, size_t ws_size,
                              hipStream_t stream) {
    const float* zf    = (const float*)d_in[0];   // [P, D]
    const float* zo    = (const float*)d_in[1];   // [P, D]
    const int*   scope = (const int*)d_in[2];     // [N, K]
    const float* W     = (const float*)d_in[3];   // [2D, 1]
    float* out = (float*)d_out;                   // [(N+1), D]

    const int N = in_sizes[2] / KK;
    const int nrows = N + 1;
    const int grid = (nrows + 3) / 4;             // 4 rows (waves) per block
    fused_gat_kernel<<<grid, 256, 0, stream>>>(zf, zo, scope, W, out, nrows);
}

// Round 6
// 67.124 us; speedup vs baseline: 2.0643x; 1.0761x over previous
//
#include <hip/hip_runtime.h>
#include <float.h>
#include <math.h>

#define KP 500000
#define KN 25000
#define KK 30
#define KD 128

// ---------------------------------------------------------------------------
// Fully fused GAT layer, pipelined edition. One 64-lane wave per output row.
// Wave = two 32-lane halves; iteration t: half h processes neighbor k = 2t+h.
//   - lane owns 4 columns (c = (lane&31)*4); float4 loads (1 KB / wave / inst)
//   - e_k = softplus(zf[ik]·W1 + zo[ik]·W2): per-half 5-round butterfly
//   - un-normalized softmax (e in (0,~8], exp(e) <= ~3e3: same ratios as the
//     max-subtracted reference, no overflow): denom += exp(e); acc += exp(e)*zo
//   - padding is TRAILING (reference pads tail) -> dynamic trip count
//     iters = ceil(deg/2), deg = popcount(ballot(idx>0)): avg 8 iters, not 15
//   - depth-1 software pipeline: issue next (a,b) loads before current compute
//   - final: merge halves via cross-half shuffles, normalize, store.
// ---------------------------------------------------------------------------
__global__ __launch_bounds__(256, 4) void fused_gat_kernel(
    const float* __restrict__ zf, const float* __restrict__ zo,
    const int* __restrict__ scope, const float* __restrict__ W,
    float* __restrict__ out, int Nrows)
{
    const int wave = threadIdx.x >> 6;
    const int lane = threadIdx.x & 63;
    const int r = blockIdx.x * 4 + wave;
    if (r >= Nrows) return;

    const int c    = (lane & 31) * 4;   // column base (same in both halves)
    const int half = lane >> 5;         // 0 or 1

    if (r == 0) {
        if (half == 0) *(float4*)(out + c) = make_float4(0.f, 0.f, 0.f, 0.f);
        return;
    }
    const long n = r - 1;

    const float4 w1 = *(const float4*)(W + c);        // W[0:128] slice
    const float4 w2 = *(const float4*)(W + KD + c);   // W[128:256] slice

    // lane k (k<30) holds this node's k-th neighbor pair index (1-based, 0=pad)
    const int idxl = (lane < KK) ? scope[n * KK + lane] : 0;

    // valid lanes are exactly 0..deg-1 (trailing padding)
    const int deg = __popcll(__ballot(idxl > 0));
    const int iters = (deg + 1) >> 1;

    float  denom = 0.f;
    float4 acc = make_float4(0.f, 0.f, 0.f, 0.f);

    // ---- pipeline prologue: load neighbor k = half ----
    int k = half;
    int ik_cur = __shfl(idxl, k, 64);
    bool v_cur = (ik_cur > 0);
    long row = v_cur ? (long)(ik_cur - 1) * KD : 0;   // pad -> row 0 (L1-hot)
    float4 a_cur = *(const float4*)(zf + row + c);
    float4 b_cur = *(const float4*)(zo + row + c);

    for (int it = 0; it < iters; ++it) {
        // ---- issue next iteration's loads first (hide latency) ----
        const int kn = k + 2;
        int ik_nxt = __shfl(idxl, (kn < KK ? kn : 0), 64);
        if (kn >= KK) ik_nxt = 0;
        const bool v_nxt = (ik_nxt > 0);
        const long rown = v_nxt ? (long)(ik_nxt - 1) * KD : 0;
        const float4 a_nxt = *(const float4*)(zf + rown + c);
        const float4 b_nxt = *(const float4*)(zo + rown + c);

        // ---- compute current neighbor ----
        float s = a_cur.x * w1.x + a_cur.y * w1.y + a_cur.z * w1.z + a_cur.w * w1.w
                + b_cur.x * w2.x + b_cur.y * w2.y + b_cur.z * w2.z + b_cur.w * w2.w;
        #pragma unroll
        for (int off = 16; off; off >>= 1)
            s += __shfl_xor(s, off, 32);              // reduce within half
        // stable softplus via fast intrinsics
        const float t = __expf(-fabsf(s));
        const float e = fmaxf(s, 0.f) + __logf(1.f + t);
        const float p = v_cur ? __expf(e) : 0.f;      // un-normalized weight
        denom += p;
        acc.x += p * b_cur.x; acc.y += p * b_cur.y;
        acc.z += p * b_cur.z; acc.w += p * b_cur.w;

        // ---- rotate pipeline ----
        a_cur = a_nxt; b_cur = b_nxt; v_cur = v_nxt; k = kn;
    }

    // merge the two halves (both end up with the full sums)
    const float od = __shfl_xor(denom, 32, 64);
    float4 oa;
    oa.x = __shfl_xor(acc.x, 32, 64);
    oa.y = __shfl_xor(acc.y, 32, 64);
    oa.z = __shfl_xor(acc.z, 32, 64);
    oa.w = __shfl_xor(acc.w, 32, 64);
    const float total = denom + od;
    const float inv = 1.f / fmaxf(total, 1e-30f);     // deg>=1 so total>0
    float4 o;
    o.x = (acc.x + oa.x) * inv;
    o.y = (acc.y + oa.y) * inv;
    o.z = (acc.z + oa.z) * inv;
    o.w = (acc.w + oa.w) * inv;

    if (half == 0)
        *(float4*)(out + (long)r * KD + c) = o;
}

extern "C" void kernel_launch(void* const* d_in, const int* in_sizes, int n_in,
                              void* d_out, int out_size, void* d_ws, size_t ws_size,
                              hipStream_t stream) {
    const float* zf    = (const float*)d_in[0];   // [P, D]
    const float* zo    = (const float*)d_in[1];   // [P, D]
    const int*   scope = (const int*)d_in[2];     // [N, K]
    const float* W     = (const float*)d_in[3];   // [2D, 1]
    float* out = (float*)d_out;                   // [(N+1), D]

    const int N = in_sizes[2] / KK;
    const int nrows = N + 1;
    const int grid = (nrows + 3) / 4;             // 4 rows (waves) per block
    fused_gat_kernel<<<grid, 256, 0, stream>>>(zf, zo, scope, W, out, nrows);
}

// Round 7
// 65.936 us; speedup vs baseline: 2.1015x; 1.0180x over previous
//
#include <hip/hip_runtime.h>
#include <float.h>
#include <math.h>

#define KP 500000
#define KN 25000
#define KK 30
#define KD 128

// ---------------------------------------------------------------------------
// Fully fused GAT layer, 4-quarter MLP edition. One 64-lane wave per row.
// Wave = four 16-lane quarters; iteration t: quarter q processes k = 4t+q.
//   - lane owns 8 columns (c = (lane&15)*8): 2x float4 from zf and zo
//     -> 4 KB of row data in flight per wave-iteration (8 KB with prefetch)
//   - e_k = softplus(zf[ik]·W1 + zo[ik]·W2): 4-round butterfly over 16 lanes
//   - un-normalized softmax (e in (0,~8], exp(e) <= ~3e3 -- same ratios as
//     max-subtracted ref): denom += exp(e); acc += exp(e) * zo_slice
//   - trailing padding -> dynamic trip count ceil(deg/4), deg via ballot
//   - depth-1 software pipeline: next loads issued before current compute
//   - final: quarter merge via xor-16 / xor-32 shuffle-adds, normalize, store.
// ---------------------------------------------------------------------------
__global__ __launch_bounds__(256, 4) void fused_gat_kernel(
    const float* __restrict__ zf, const float* __restrict__ zo,
    const int* __restrict__ scope, const float* __restrict__ W,
    float* __restrict__ out, int Nrows)
{
    const int wave = threadIdx.x >> 6;
    const int lane = threadIdx.x & 63;
    const int r = blockIdx.x * 4 + wave;
    if (r >= Nrows) return;

    const int q = lane >> 4;            // quarter 0..3
    const int c = (lane & 15) * 8;      // column base (same in all quarters)

    if (r == 0) {
        if (q == 0) {
            *(float4*)(out + c)     = make_float4(0.f, 0.f, 0.f, 0.f);
            *(float4*)(out + c + 4) = make_float4(0.f, 0.f, 0.f, 0.f);
        }
        return;
    }
    const long n = r - 1;

    const float4 w1a = *(const float4*)(W + c);
    const float4 w1b = *(const float4*)(W + c + 4);        // W[0:128] slice
    const float4 w2a = *(const float4*)(W + KD + c);
    const float4 w2b = *(const float4*)(W + KD + c + 4);   // W[128:256] slice

    // lane k (k<30) holds this node's k-th neighbor pair index (1-based, 0=pad)
    const int idxl = (lane < KK) ? scope[n * KK + lane] : 0;

    // valid lanes are exactly 0..deg-1 (trailing padding)
    const int deg = __popcll(__ballot(idxl > 0));
    const int iters = (deg + 3) >> 2;

    float  denom = 0.f;
    float4 acca = make_float4(0.f, 0.f, 0.f, 0.f);
    float4 accb = make_float4(0.f, 0.f, 0.f, 0.f);

    // ---- pipeline prologue: neighbor k = q ----
    int k = q;
    int ik_cur = __shfl(idxl, k, 64);
    bool v_cur = (ik_cur > 0);
    long row = v_cur ? (long)(ik_cur - 1) * KD : 0;   // pad -> row 0 (L1-hot)
    float4 a0 = *(const float4*)(zf + row + c);
    float4 a1 = *(const float4*)(zf + row + c + 4);
    float4 b0 = *(const float4*)(zo + row + c);
    float4 b1 = *(const float4*)(zo + row + c + 4);

    for (int it = 0; it < iters; ++it) {
        // ---- issue next iteration's loads first (hide latency) ----
        const int kn = k + 4;
        int ik_nxt = __shfl(idxl, (kn < KK ? kn : 0), 64);
        if (kn >= KK) ik_nxt = 0;
        const bool v_nxt = (ik_nxt > 0);
        const long rown = v_nxt ? (long)(ik_nxt - 1) * KD : 0;
        const float4 na0 = *(const float4*)(zf + rown + c);
        const float4 na1 = *(const float4*)(zf + rown + c + 4);
        const float4 nb0 = *(const float4*)(zo + rown + c);
        const float4 nb1 = *(const float4*)(zo + rown + c + 4);

        // ---- compute current neighbor ----
        float s = a0.x * w1a.x + a0.y * w1a.y + a0.z * w1a.z + a0.w * w1a.w
                + a1.x * w1b.x + a1.y * w1b.y + a1.z * w1b.z + a1.w * w1b.w
                + b0.x * w2a.x + b0.y * w2a.y + b0.z * w2a.z + b0.w * w2a.w
                + b1.x * w2b.x + b1.y * w2b.y + b1.z * w2b.z + b1.w * w2b.w;
        #pragma unroll
        for (int off = 8; off; off >>= 1)
            s += __shfl_xor(s, off, 16);              // reduce within quarter
        // stable softplus via fast intrinsics
        const float t = __expf(-fabsf(s));
        const float e = fmaxf(s, 0.f) + __logf(1.f + t);
        const float p = v_cur ? __expf(e) : 0.f;      // un-normalized weight
        denom += p;
        acca.x += p * b0.x; acca.y += p * b0.y;
        acca.z += p * b0.z; acca.w += p * b0.w;
        accb.x += p * b1.x; accb.y += p * b1.y;
        accb.z += p * b1.z; accb.w += p * b1.w;

        // ---- rotate pipeline ----
        a0 = na0; a1 = na1; b0 = nb0; b1 = nb1; v_cur = v_nxt; k = kn;
    }

    // merge the four quarters (xor 16 then xor 32)
    #pragma unroll
    for (int off = 16; off <= 32; off <<= 1) {
        denom  += __shfl_xor(denom,  off, 64);
        acca.x += __shfl_xor(acca.x, off, 64);
        acca.y += __shfl_xor(acca.y, off, 64);
        acca.z += __shfl_xor(acca.z, off, 64);
        acca.w += __shfl_xor(acca.w, off, 64);
        accb.x += __shfl_xor(accb.x, off, 64);
        accb.y += __shfl_xor(accb.y, off, 64);
        accb.z += __shfl_xor(accb.z, off, 64);
        accb.w += __shfl_xor(accb.w, off, 64);
    }
    const float inv = 1.f / fmaxf(denom, 1e-30f);     // deg>=1 so denom>0

    if (q == 0) {
        float4 oa, ob;
        oa.x = acca.x * inv; oa.y = acca.y * inv;
        oa.z = acca.z * inv; oa.w = acca.w * inv;
        ob.x = accb.x * inv; ob.y = accb.y * inv;
        ob.z = accb.z * inv; ob.w = accb.w * inv;
        *(float4*)(out + (long)r * KD + c)     = oa;
        *(float4*)(out + (long)r * KD + c + 4) = ob;
    }
}

extern "C" void kernel_launch(void* const* d_in, const int* in_sizes, int n_in,
                              void* d_out, int out_size, void* d_ws, size_t ws_size,
                              hipStream_t stream) {
    const float* zf    = (const float*)d_in[0];   // [P, D]
    const float* zo    = (const float*)d_in[1];   // [P, D]
    const int*   scope = (const int*)d_in[2];     // [N, K]
    const float* W     = (const float*)d_in[3];   // [2D, 1]
    float* out = (float*)d_out;                   // [(N+1), D]

    const int N = in_sizes[2] / KK;
    const int nrows = N + 1;
    const int grid = (nrows + 3) / 4;             // 4 rows (waves) per block
    fused_gat_kernel<<<grid, 256, 0, stream>>>(zf, zo, scope, W, out, nrows);
}